// Round 6
// baseline (339.950 us; speedup 1.0000x reference)
//
#include <hip/hip_runtime.h>
#include <hip/hip_bf16.h>

typedef unsigned short u16;

#define B_    4
#define T_    4096
#define C_    512
#define H_    8
#define D_    64
#define WIN_  15
#define PAD_  7
#define M_    (B_*T_)      // 16384 rows
#define NQKV  1536
#define KDIM  512

typedef __bf16 bf16x8 __attribute__((ext_vector_type(8)));
typedef float  f32x4  __attribute__((ext_vector_type(4)));

__device__ __forceinline__ u16 f2bf(float f) {
    union { float f; unsigned int i; } c; c.f = f;
    unsigned int lsb = (c.i >> 16) & 1u;
    c.i += 0x7fffu + lsb;                 // round-to-nearest-even
    return (u16)(c.i >> 16);
}
__device__ __forceinline__ float bf2f(u16 u) {
    union { unsigned int i; float f; } c; c.i = ((unsigned int)u) << 16; return c.f;
}
__device__ __forceinline__ uint4 cvt8(const float4 a, const float4 b, float m) {
    union { uint4 u; u16 s[8]; } o;
    o.s[0] = f2bf(a.x * m); o.s[1] = f2bf(a.y * m);
    o.s[2] = f2bf(a.z * m); o.s[3] = f2bf(a.w * m);
    o.s[4] = f2bf(b.x * m); o.s[5] = f2bf(b.y * m);
    o.s[6] = f2bf(b.z * m); o.s[7] = f2bf(b.w * m);
    return o.u;
}

// ---------------------------------------------------------------------------
// Pack fp32 weights -> bf16 transposed Wt[n][k].
// Wt_qkv rows: [0,512)=Wq cols, [512,1024)=Wkv k-part, [1024,1536)=Wkv v-part.
// ---------------------------------------------------------------------------
__global__ void pack_weights(const float* __restrict__ Wq, const float* __restrict__ Wkv,
                             const float* __restrict__ Wp,
                             u16* __restrict__ Wt_qkv, u16* __restrict__ Wpt)
{
    int idx = blockIdx.x * blockDim.x + threadIdx.x;   // 0 .. 1536*512-1
    int n = idx >> 9;
    int k = idx & 511;
    float w = (n < 512) ? Wq[k * 512 + n] : Wkv[k * 1024 + (n - 512)];
    Wt_qkv[idx] = f2bf(w);
    if (idx < 512 * 512) Wpt[idx] = f2bf(Wp[k * 512 + n]);
}

// ---------------------------------------------------------------------------
// 128x128 tile MFMA GEMM, C = A(MxK) * Bt(NxK)^T + bias.
// A_FP32_MASK: A is fp32 (row stride lda floats); rows scaled by amask[row]
//   and converted to bf16 during LDS staging. Else A is bf16 stride lda.
// USE_MASK: epilogue multiplies by amask[row] (fp32).
// OUT_F32:  C written as fp32, else bf16.
// Bias fp32: col<512 -> bias0[col], else bias1[col-512].
// 4 waves, each computes a 64x64 quadrant via 4x4 16x16x32 bf16 MFMA frags.
// ---------------------------------------------------------------------------
template<bool A_FP32_MASK, bool USE_MASK, bool OUT_F32>
__global__ __launch_bounds__(256) void gemm_bt_128(
    const void* __restrict__ Av, int lda,
    const float* __restrict__ amask,  // M fp32
    const u16* __restrict__ Bt,       // N x K row-major bf16 (pre-transposed)
    const float* __restrict__ bias0, const float* __restrict__ bias1,
    void* __restrict__ Cc,            // M x N row-major
    int K, int N)
{
    __shared__ __align__(16) u16 As[128 * 32];
    __shared__ __align__(16) u16 Bs[128 * 32];

    const int tid  = threadIdx.x;
    const int wave = tid >> 6;
    const int lane = tid & 63;
    const int row0 = blockIdx.x * 128;
    const int col0 = blockIdx.y * 128;
    const int wm = (wave >> 1) * 64;   // wave's row offset in tile
    const int wn = (wave & 1) * 64;    // wave's col offset in tile

    f32x4 acc[4][4] = {};

    // chunk c in [0,512): 16B = 8 bf16; tile row = c>>2, k-subcol = c&3
    const int c0 = tid;
    const int c1 = tid + 256;
    const int r0g = row0 + (c0 >> 2), s0 = c0 & 3;
    const int r1g = row0 + (c1 >> 2), s1 = c1 & 3;

    float m0 = 1.f, m1 = 1.f;
    if (A_FP32_MASK) { m0 = amask[r0g]; m1 = amask[r1g]; }

    const u16* Bb = Bt + (size_t)col0 * K;
    const int quad = lane >> 4;
    const int l16  = lane & 15;

    for (int k0 = 0; k0 < K; k0 += 32) {
        uint4 ra0, ra1;
        if (A_FP32_MASK) {
            const float* A0 = (const float*)Av + (size_t)r0g * lda + k0 + s0 * 8;
            const float* A1 = (const float*)Av + (size_t)r1g * lda + k0 + s1 * 8;
            ra0 = cvt8(*(const float4*)A0, *(const float4*)(A0 + 4), m0);
            ra1 = cvt8(*(const float4*)A1, *(const float4*)(A1 + 4), m1);
        } else {
            ra0 = *(const uint4*)((const u16*)Av + (size_t)r0g * lda + k0 + s0 * 8);
            ra1 = *(const uint4*)((const u16*)Av + (size_t)r1g * lda + k0 + s1 * 8);
        }
        uint4 rb0 = *(const uint4*)(Bb + (size_t)(c0 >> 2) * K + k0 + s0 * 8);
        uint4 rb1 = *(const uint4*)(Bb + (size_t)(c1 >> 2) * K + k0 + s1 * 8);

        __syncthreads();   // all waves done reading LDS from previous iter
        *(uint4*)&As[c0 * 8] = ra0;
        *(uint4*)&As[c1 * 8] = ra1;
        *(uint4*)&Bs[c0 * 8] = rb0;
        *(uint4*)&Bs[c1 * 8] = rb1;
        __syncthreads();   // staging visible to all waves

        bf16x8 a[4], b[4];
        #pragma unroll
        for (int i = 0; i < 4; i++) {
            a[i] = *(const bf16x8*)&As[(wm + i * 16 + l16) * 32 + quad * 8];
            b[i] = *(const bf16x8*)&Bs[(wn + i * 16 + l16) * 32 + quad * 8];
        }
        #pragma unroll
        for (int mi = 0; mi < 4; mi++)
            #pragma unroll
            for (int ni = 0; ni < 4; ni++)
                acc[mi][ni] = __builtin_amdgcn_mfma_f32_16x16x32_bf16(
                    a[mi], b[ni], acc[mi][ni], 0, 0, 0);
    }

    // epilogue: C/D layout col=lane&15, row=quad*4+reg  [m89-verified]
    #pragma unroll
    for (int mi = 0; mi < 4; mi++) {
        #pragma unroll
        for (int ni = 0; ni < 4; ni++) {
            int col = col0 + wn + ni * 16 + l16;
            float bval = (col < 512) ? bias0[col] : bias1[col - 512];
            #pragma unroll
            for (int r = 0; r < 4; r++) {
                int row = row0 + wm + mi * 16 + quad * 4 + r;
                float v = acc[mi][ni][r] + bval;
                if (USE_MASK) v *= amask[row];
                if (OUT_F32) ((float*)Cc)[(size_t)row * N + col] = v;
                else         ((u16*)Cc)[(size_t)row * N + col] = f2bf(v);
            }
        }
    }
}

// ---------------------------------------------------------------------------
// Windowed attention: one wave per (b*T+t, h); lane = d in [0,64).
// k/v at padded positions == bkv bias (zero row through affine map).
// Writes output IN PLACE over the q section of qkv (cols [0,512)): q[m,h,:]
// is read only by wave (m,h) before its own write; k/v cols never written.
// ---------------------------------------------------------------------------
__global__ __launch_bounds__(256) void attn_win(u16* __restrict__ qkv,
                                                const float* __restrict__ bkv)
{
    const int gw   = (blockIdx.x * blockDim.x + threadIdx.x) >> 6;
    const int lane = threadIdx.x & 63;
    const int h = gw & (H_ - 1);
    const int m = gw >> 3;          // b*T + t
    const int t = m & (T_ - 1);

    const size_t base = (size_t)m * NQKV + h * 64 + lane;
    const float qv = bf2f(qkv[base]);
    const float kb = bkv[h * 64 + lane];
    const float vb = bkv[512 + h * 64 + lane];
    const float scale = 0.042313283f;   // ln(15)/64

    float s[WIN_];
    #pragma unroll
    for (int w = 0; w < WIN_; w++) {
        int tp = t + w - PAD_;
        float kv = (tp >= 0 && tp < T_)
                 ? bf2f(qkv[base + (long)(w - PAD_) * NQKV + 512]) : kb;
        float p = qv * kv;
        #pragma unroll
        for (int off = 32; off > 0; off >>= 1) p += __shfl_xor(p, off, 64);
        s[w] = p * scale;
    }
    float mx = s[0];
    #pragma unroll
    for (int w = 1; w < WIN_; w++) mx = fmaxf(mx, s[w]);
    float sum = 0.f;
    #pragma unroll
    for (int w = 0; w < WIN_; w++) { s[w] = expf(s[w] - mx); sum += s[w]; }
    const float inv = 1.0f / sum;

    float o = 0.f;
    #pragma unroll
    for (int w = 0; w < WIN_; w++) {
        int tp = t + w - PAD_;
        float vv = (tp >= 0 && tp < T_)
                 ? bf2f(qkv[base + (long)(w - PAD_) * NQKV + 1024]) : vb;
        o += s[w] * vv;
    }
    qkv[base] = f2bf(o * inv);          // overwrite q slot with attention out
}

// ---------------------------------------------------------------------------
// Workspace: 50 MiB total.
//   [0, 1.5Mi)    Wt_qkv (1536x512 bf16)
//   [1.5Mi, 2Mi)  Wpt    (512x512 bf16)
//   [2Mi, 50Mi)   qkv    (16384x1536 bf16); q section reused for attn output
// ---------------------------------------------------------------------------
extern "C" void kernel_launch(void* const* d_in, const int* in_sizes, int n_in,
                              void* d_out, int out_size, void* d_ws, size_t ws_size,
                              hipStream_t stream)
{
    const float* x    = (const float*)d_in[0];
    const float* mask = (const float*)d_in[1];
    const float* Wq   = (const float*)d_in[2];
    const float* bq   = (const float*)d_in[3];
    const float* Wkv  = (const float*)d_in[4];
    const float* bkv  = (const float*)d_in[5];
    const float* Wp   = (const float*)d_in[6];
    const float* bp   = (const float*)d_in[7];
    float* out = (float*)d_out;

    char* ws = (char*)d_ws;
    u16* Wt_qkv = (u16*)(ws);
    u16* Wpt    = (u16*)(ws + (size_t)(1536 * 1024));
    u16* qkv    = (u16*)(ws + (size_t)(2048 * 1024));

    pack_weights<<<NQKV * KDIM / 256, 256, 0, stream>>>(Wq, Wkv, Wp, Wt_qkv, Wpt);

    dim3 g1(M_ / 128, NQKV / 128);
    gemm_bt_128<true, false, false><<<g1, 256, 0, stream>>>(
        x, KDIM, mask, Wt_qkv, bq, bkv, qkv, KDIM, NQKV);

    attn_win<<<(M_ * H_) / 4, 256, 0, stream>>>(qkv, bkv);

    dim3 g2(M_ / 128, C_ / 128);
    gemm_bt_128<false, true, true><<<g2, 256, 0, stream>>>(
        qkv, NQKV, mask, Wpt, bp, nullptr, out, KDIM, C_);
}

// Round 7
// 196.018 us; speedup vs baseline: 1.7343x; 1.7343x over previous
//
#include <hip/hip_runtime.h>
#include <hip/hip_bf16.h>

typedef unsigned short u16;

#define B_    4
#define T_    4096
#define C_    512
#define H_    8
#define D_    64
#define WIN_  15
#define PAD_  7
#define M_    (B_*T_)      // 16384 rows
#define NQKV  1536
#define KDIM  512

typedef __bf16 bf16x8 __attribute__((ext_vector_type(8)));
typedef float  f32x4  __attribute__((ext_vector_type(4)));

__device__ __forceinline__ u16 f2bf(float f) {
    union { float f; unsigned int i; } c; c.f = f;
    unsigned int lsb = (c.i >> 16) & 1u;
    c.i += 0x7fffu + lsb;                 // round-to-nearest-even
    return (u16)(c.i >> 16);
}
__device__ __forceinline__ float bf2f(u16 u) {
    union { unsigned int i; float f; } c; c.i = ((unsigned int)u) << 16; return c.f;
}
__device__ __forceinline__ uint4 cvt8(const float4 a, const float4 b, float m) {
    union { uint4 u; u16 s[8]; } o;
    o.s[0] = f2bf(a.x * m); o.s[1] = f2bf(a.y * m);
    o.s[2] = f2bf(a.z * m); o.s[3] = f2bf(a.w * m);
    o.s[4] = f2bf(b.x * m); o.s[5] = f2bf(b.y * m);
    o.s[6] = f2bf(b.z * m); o.s[7] = f2bf(b.w * m);
    return o.u;
}

// ---------------------------------------------------------------------------
// Pack fp32 weights -> bf16 transposed Wt[n][k].
// Wt_qkv rows: [0,512)=Wq cols, [512,1024)=Wkv k-part, [1024,1536)=Wkv v-part.
// ---------------------------------------------------------------------------
__global__ void pack_weights(const float* __restrict__ Wq, const float* __restrict__ Wkv,
                             const float* __restrict__ Wp,
                             u16* __restrict__ Wt_qkv, u16* __restrict__ Wpt)
{
    int idx = blockIdx.x * blockDim.x + threadIdx.x;   // 0 .. 1536*512-1
    int n = idx >> 9;
    int k = idx & 511;
    float w = (n < 512) ? Wq[k * 512 + n] : Wkv[k * 1024 + (n - 512)];
    Wt_qkv[idx] = f2bf(w);
    if (idx < 512 * 512) Wpt[idx] = f2bf(Wp[k * 512 + n]);
}

// ---------------------------------------------------------------------------
// 128x128 tile MFMA GEMM, C = A(MxK) * Bt(NxK)^T + bias.
// A_FP32_MASK: A is fp32 (row stride lda floats); rows scaled by amask[row]
//   and converted to bf16 during LDS staging. Else A is bf16 stride lda.
// USE_MASK: epilogue multiplies by amask[row] (fp32).
// OUT_F32:  C written as fp32, else bf16.
// Bias fp32: col<512 -> bias0[col], else bias1[col-512].
// 4 waves, each computes a 64x64 quadrant via 4x4 16x16x32 bf16 MFMA frags.
// ---------------------------------------------------------------------------
template<bool A_FP32_MASK, bool USE_MASK, bool OUT_F32>
__global__ __launch_bounds__(256) void gemm_bt_128(
    const void* __restrict__ Av, int lda,
    const float* __restrict__ amask,  // M fp32
    const u16* __restrict__ Bt,       // N x K row-major bf16 (pre-transposed)
    const float* __restrict__ bias0, const float* __restrict__ bias1,
    void* __restrict__ Cc,            // M x N row-major
    int K, int N)
{
    __shared__ __align__(16) u16 As[128 * 32];
    __shared__ __align__(16) u16 Bs[128 * 32];

    const int tid  = threadIdx.x;
    const int wave = tid >> 6;
    const int lane = tid & 63;
    const int row0 = blockIdx.x * 128;
    const int col0 = blockIdx.y * 128;
    const int wm = (wave >> 1) * 64;   // wave's row offset in tile
    const int wn = (wave & 1) * 64;    // wave's col offset in tile

    f32x4 acc[4][4] = {};

    // chunk c in [0,512): 16B = 8 bf16; tile row = c>>2, k-subcol = c&3
    const int c0 = tid;
    const int c1 = tid + 256;
    const int r0g = row0 + (c0 >> 2), s0 = c0 & 3;
    const int r1g = row0 + (c1 >> 2), s1 = c1 & 3;

    float m0 = 1.f, m1 = 1.f;
    if (A_FP32_MASK) { m0 = amask[r0g]; m1 = amask[r1g]; }

    const u16* Bb = Bt + (size_t)col0 * K;
    const int quad = lane >> 4;
    const int l16  = lane & 15;

    for (int k0 = 0; k0 < K; k0 += 32) {
        uint4 ra0, ra1;
        if (A_FP32_MASK) {
            const float* A0 = (const float*)Av + (size_t)r0g * lda + k0 + s0 * 8;
            const float* A1 = (const float*)Av + (size_t)r1g * lda + k0 + s1 * 8;
            ra0 = cvt8(*(const float4*)A0, *(const float4*)(A0 + 4), m0);
            ra1 = cvt8(*(const float4*)A1, *(const float4*)(A1 + 4), m1);
        } else {
            ra0 = *(const uint4*)((const u16*)Av + (size_t)r0g * lda + k0 + s0 * 8);
            ra1 = *(const uint4*)((const u16*)Av + (size_t)r1g * lda + k0 + s1 * 8);
        }
        uint4 rb0 = *(const uint4*)(Bb + (size_t)(c0 >> 2) * K + k0 + s0 * 8);
        uint4 rb1 = *(const uint4*)(Bb + (size_t)(c1 >> 2) * K + k0 + s1 * 8);

        __syncthreads();   // all waves done reading LDS from previous iter
        *(uint4*)&As[c0 * 8] = ra0;
        *(uint4*)&As[c1 * 8] = ra1;
        *(uint4*)&Bs[c0 * 8] = rb0;
        *(uint4*)&Bs[c1 * 8] = rb1;
        __syncthreads();   // staging visible to all waves

        bf16x8 a[4], b[4];
        #pragma unroll
        for (int i = 0; i < 4; i++) {
            a[i] = *(const bf16x8*)&As[(wm + i * 16 + l16) * 32 + quad * 8];
            b[i] = *(const bf16x8*)&Bs[(wn + i * 16 + l16) * 32 + quad * 8];
        }
        #pragma unroll
        for (int mi = 0; mi < 4; mi++)
            #pragma unroll
            for (int ni = 0; ni < 4; ni++)
                acc[mi][ni] = __builtin_amdgcn_mfma_f32_16x16x32_bf16(
                    a[mi], b[ni], acc[mi][ni], 0, 0, 0);
    }

    // epilogue: C/D layout col=lane&15, row=quad*4+reg  [m89-verified]
    #pragma unroll
    for (int mi = 0; mi < 4; mi++) {
        #pragma unroll
        for (int ni = 0; ni < 4; ni++) {
            int col = col0 + wn + ni * 16 + l16;
            float bval = (col < 512) ? bias0[col] : bias1[col - 512];
            #pragma unroll
            for (int r = 0; r < 4; r++) {
                int row = row0 + wm + mi * 16 + quad * 4 + r;
                float v = acc[mi][ni][r] + bval;
                if (USE_MASK) v *= amask[row];
                if (OUT_F32) ((float*)Cc)[(size_t)row * N + col] = v;
                else         ((u16*)Cc)[(size_t)row * N + col] = f2bf(v);
            }
        }
    }
}

// ---------------------------------------------------------------------------
// Windowed attention v2: thread-per-(t,h). Block = 256 consecutive t, one
// (b,h). k/v h-slices staged in LDS layout [jchunk][row] so the compute
// loop issues stride-1 ds_read_b128 across lanes (optimal LDS pattern, no
// bank conflicts, no cross-lane reduction at all). Rows outside [0,T) get
// the bias row (zero-padded x through the affine map) at staging time.
// Output written in place over the q slot (thread owns its row; k/v cols
// never written -> no hazard).
// ---------------------------------------------------------------------------
__global__ __launch_bounds__(256) void attn_win2(u16* __restrict__ qkv,
                                                 const float* __restrict__ bkv)
{
    __shared__ uint4 klds[8 * 270];   // [j][row], row = t0-7+row, 34.56 KB
    __shared__ uint4 vlds[8 * 270];

    const int tid = threadIdx.x;
    const int bid = blockIdx.x;
    const int h  = bid & 7;
    const int b  = (bid >> 3) & 3;
    const int tb = bid >> 5;          // [0,16)
    const int t0 = tb * 256;

    // ---- stage k/v rows t0-7 .. t0+262 (270 rows x 8 chunks of 16B) ----
    #pragma unroll
    for (int i = 0; i < 9; i++) {
        int idx = i * 256 + tid;      // linear in LDS layout [j][row]
        if (idx < 2160) {
            int row = idx % 270;
            int j   = idx / 270;
            int tt  = t0 - 7 + row;
            uint4 kc, vc;
            if ((unsigned)tt < (unsigned)T_) {
                const u16* g = qkv + ((size_t)b * T_ + tt) * NQKV + 512 + h * 64 + j * 8;
                kc = *(const uint4*)g;
                vc = *(const uint4*)(g + 512);
            } else {
                union { uint4 u; u16 s[8]; } pk, pv;
                #pragma unroll
                for (int e = 0; e < 8; e++) {
                    pk.s[e] = f2bf(bkv[h * 64 + j * 8 + e]);
                    pv.s[e] = f2bf(bkv[512 + h * 64 + j * 8 + e]);
                }
                kc = pk.u; vc = pv.u;
            }
            klds[j * 270 + row] = kc;
            vlds[j * 270 + row] = vc;
        }
    }
    __syncthreads();

    // ---- per-thread: full attention row for (m = b*T + t0 + tid, h) ----
    const size_t m = (size_t)b * T_ + t0 + tid;
    u16* qrow = qkv + m * NQKV + h * 64;

    float qf[64];
    #pragma unroll
    for (int j = 0; j < 8; j++) {
        union { uint4 u; u16 s[8]; } t;
        t.u = *(const uint4*)(qrow + j * 8);
        #pragma unroll
        for (int e = 0; e < 8; e++) qf[j * 8 + e] = bf2f(t.s[e]);
    }

    const float scale = 0.042313283f;   // ln(15)/64
    float s[WIN_];
    #pragma unroll
    for (int w = 0; w < WIN_; w++) {
        float acc = 0.f;
        #pragma unroll
        for (int j = 0; j < 8; j++) {
            union { uint4 u; u16 e[8]; } kc;
            kc.u = klds[j * 270 + tid + w];   // lanes: consecutive rows
            #pragma unroll
            for (int e2 = 0; e2 < 8; e2++)
                acc += qf[j * 8 + e2] * bf2f(kc.e[e2]);
        }
        s[w] = acc * scale;
    }

    float mx = s[0];
    #pragma unroll
    for (int w = 1; w < WIN_; w++) mx = fmaxf(mx, s[w]);
    float sum = 0.f;
    #pragma unroll
    for (int w = 0; w < WIN_; w++) { s[w] = __expf(s[w] - mx); sum += s[w]; }
    const float inv = 1.0f / sum;
    #pragma unroll
    for (int w = 0; w < WIN_; w++) s[w] *= inv;

    #pragma unroll
    for (int j = 0; j < 8; j++) {
        float o[8] = {};
        #pragma unroll
        for (int w = 0; w < WIN_; w++) {
            union { uint4 u; u16 e[8]; } vc;
            vc.u = vlds[j * 270 + tid + w];
            #pragma unroll
            for (int e2 = 0; e2 < 8; e2++) o[e2] += s[w] * bf2f(vc.e[e2]);
        }
        union { uint4 u; u16 e[8]; } oc;
        #pragma unroll
        for (int e2 = 0; e2 < 8; e2++) oc.e[e2] = f2bf(o[e2]);
        *(uint4*)(qrow + j * 8) = oc.u;   // overwrite own q slot
    }
}

// ---------------------------------------------------------------------------
// Workspace: 50 MiB total.
//   [0, 1.5Mi)    Wt_qkv (1536x512 bf16)
//   [1.5Mi, 2Mi)  Wpt    (512x512 bf16)
//   [2Mi, 50Mi)   qkv    (16384x1536 bf16); q section reused for attn output
// ---------------------------------------------------------------------------
extern "C" void kernel_launch(void* const* d_in, const int* in_sizes, int n_in,
                              void* d_out, int out_size, void* d_ws, size_t ws_size,
                              hipStream_t stream)
{
    const float* x    = (const float*)d_in[0];
    const float* mask = (const float*)d_in[1];
    const float* Wq   = (const float*)d_in[2];
    const float* bq   = (const float*)d_in[3];
    const float* Wkv  = (const float*)d_in[4];
    const float* bkv  = (const float*)d_in[5];
    const float* Wp   = (const float*)d_in[6];
    const float* bp   = (const float*)d_in[7];
    float* out = (float*)d_out;

    char* ws = (char*)d_ws;
    u16* Wt_qkv = (u16*)(ws);
    u16* Wpt    = (u16*)(ws + (size_t)(1536 * 1024));
    u16* qkv    = (u16*)(ws + (size_t)(2048 * 1024));

    pack_weights<<<NQKV * KDIM / 256, 256, 0, stream>>>(Wq, Wkv, Wp, Wt_qkv, Wpt);

    dim3 g1(M_ / 128, NQKV / 128);
    gemm_bt_128<true, false, false><<<g1, 256, 0, stream>>>(
        x, KDIM, mask, Wt_qkv, bq, bkv, qkv, KDIM, NQKV);

    attn_win2<<<(T_ / 256) * B_ * H_, 256, 0, stream>>>(qkv, bkv);

    dim3 g2(M_ / 128, C_ / 128);
    gemm_bt_128<false, true, true><<<g2, 256, 0, stream>>>(
        qkv, NQKV, mask, Wpt, bp, nullptr, out, KDIM, C_);
}